// Round 1
// baseline (1065.576 us; speedup 1.0000x reference)
//
#include <hip/hip_runtime.h>
#include <math.h>
#include <float.h>

#define NB 8
#define NP 4096
#define BN (NB*NP)
#define KNN 5

// ---------------- preprocessing ----------------

__global__ void k_centroid(const float* __restrict__ pc, float* __restrict__ dcent) {
  int b = blockIdx.x, tid = threadIdx.x;
  const float* px = pc + (size_t)b*3*NP;
  const float* py = px + NP;
  const float* pz = py + NP;
  double sx=0, sy=0, sz=0;
  for (int n = tid; n < NP; n += 256) { sx += px[n]; sy += py[n]; sz += pz[n]; }
  __shared__ double rx[256], ry[256], rz[256];
  rx[tid]=sx; ry[tid]=sy; rz[tid]=sz;
  __syncthreads();
  for (int s = 128; s > 0; s >>= 1) {
    if (tid < s) { rx[tid]+=rx[tid+s]; ry[tid]+=ry[tid+s]; rz[tid]+=rz[tid+s]; }
    __syncthreads();
  }
  __shared__ float cxs, cys, czs;
  if (tid == 0) {
    cxs = (float)(rx[0]/NP); cys = (float)(ry[0]/NP); czs = (float)(rz[0]/NP);
  }
  __syncthreads();
  float cx = cxs, cy = cys, cz = czs;
  for (int n = tid; n < NP; n += 256) {
    float dx = __fsub_rn(px[n], cx);
    float dy = __fsub_rn(py[n], cy);
    float dz = __fsub_rn(pz[n], cz);
    float d = __fadd_rn(__fadd_rn(__fmul_rn(dx,dx), __fmul_rn(dy,dy)), __fmul_rn(dz,dz));
    dcent[b*NP + n] = d;
  }
}

// stable argsort via rank counting (key = (d, index) lexicographic)
__global__ void k_rank(const float* __restrict__ dcent, int* __restrict__ ord) {
  int b = blockIdx.x >> 4, chunk = blockIdx.x & 15;
  __shared__ float d[NP];
  for (int n = threadIdx.x; n < NP; n += 256) d[n] = dcent[b*NP + n];
  __syncthreads();
  int i = chunk*256 + threadIdx.x;
  float di = d[i];
  int rank = 0;
  #pragma unroll 4
  for (int j = 0; j < NP; ++j) {
    float dj = d[j];
    rank += (dj < di) || (dj == di && j < i);
  }
  ord[b*NP + rank] = i;
}

__global__ void __launch_bounds__(256) k_knn(const float* __restrict__ pc,
                                             int* __restrict__ nbr,
                                             int* __restrict__ deg) {
  int b = blockIdx.x >> 4, chunk = blockIdx.x & 15;
  __shared__ float xs[NP], ys[NP], zs[NP];
  const float* px = pc + (size_t)b*3*NP;
  for (int n = threadIdx.x; n < NP; n += 256) {
    xs[n] = px[n]; ys[n] = px[NP+n]; zs[n] = px[2*NP+n];
  }
  __syncthreads();
  int i = chunk*256 + threadIdx.x;
  float xi = xs[i], yi = ys[i], zi = zs[i];
  float sqi = __fadd_rn(__fadd_rn(__fmul_rn(xi,xi), __fmul_rn(yi,yi)), __fmul_rn(zi,zi));
  float b0 = FLT_MAX, b1 = FLT_MAX, b2 = FLT_MAX, b3 = FLT_MAX, b4 = FLT_MAX;
  int   i0 = 0, i1 = 0, i2 = 0, i3 = 0, i4 = 0;
  #pragma unroll 4
  for (int j = 0; j < NP; ++j) {
    float xj = xs[j], yj = ys[j], zj = zs[j];
    float sqj = __fadd_rn(__fadd_rn(__fmul_rn(xj,xj), __fmul_rn(yj,yj)), __fmul_rn(zj,zj));
    float dot = __fadd_rn(__fadd_rn(__fmul_rn(xi,xj), __fmul_rn(yi,yj)), __fmul_rn(zi,zj));
    float dist = __fsub_rn(__fadd_rn(sqi, sqj), __fmul_rn(2.0f, dot));
    if (dist < b4) {                 // strict < : equal keeps earlier index (top_k tie rule)
      if (dist < b3) {
        b4 = b3; i4 = i3;
        if (dist < b2) {
          b3 = b2; i3 = i2;
          if (dist < b1) {
            b2 = b1; i2 = i1;
            if (dist < b0) { b1 = b0; i1 = i0; b0 = dist; i0 = j; }
            else           { b1 = dist; i1 = j; }
          } else { b2 = dist; i2 = j; }
        } else { b3 = dist; i3 = j; }
      } else { b4 = dist; i4 = j; }
    }
  }
  int node = b*NP + i;
  int base = node*KNN;
  nbr[base+0] = b*NP + i0;  nbr[base+1] = b*NP + i1;  nbr[base+2] = b*NP + i2;
  nbr[base+3] = b*NP + i3;  nbr[base+4] = b*NP + i4;
  atomicAdd(&deg[b*NP + i0], 1); atomicAdd(&deg[b*NP + i1], 1);
  atomicAdd(&deg[b*NP + i2], 1); atomicAdd(&deg[b*NP + i3], 1);
  atomicAdd(&deg[b*NP + i4], 1);
}

__global__ void k_norm(const int* __restrict__ deg, float* __restrict__ normo) {
  int i = blockIdx.x*256 + threadIdx.x;
  int d = deg[i]; if (d < 1) d = 1;
  normo[i] = 1.0f / sqrtf((float)d);
}

// ---------------- conv1 (3 -> 64) on sorted points ----------------
__global__ void k_conv1(const float* __restrict__ pc, const int* __restrict__ ord,
                        const float* __restrict__ w, const float* __restrict__ g,
                        const float* __restrict__ bias, float* __restrict__ out) {
  int node = blockIdx.x*4 + (threadIdx.x >> 6);
  int o = threadIdx.x & 63;
  int b = node >> 12;
  int j = ord[node];
  const float* base = pc + (size_t)b*3*NP;
  float x = base[j], y = base[NP + j], z = base[2*NP + j];
  float acc = x*w[o*3+0] + y*w[o*3+1] + z*w[o*3+2];
  float v = acc*g[o] + bias[o];
  out[(size_t)node*64 + o] = fmaxf(v, 0.0f);
}

// ---------------- generic fp32 GEMMs, 64x64 tile, 256 thr, 4x4 micro ----------------
// C[m,o] = act((sum_k A[m,k]*W[o,k]) * g[o] + b[o])
__global__ void __launch_bounds__(256) gemm_nt(const float* __restrict__ A,
    const float* __restrict__ W, const float* __restrict__ g, const float* __restrict__ bias,
    float* __restrict__ C, int K, int Nc, int do_relu) {
  __shared__ __attribute__((aligned(16))) float As[16][68];
  __shared__ __attribute__((aligned(16))) float Bs[16][68];
  int tid = threadIdx.x;
  int m0 = blockIdx.x * 64, n0 = blockIdx.y * 64;
  int ty = tid >> 4, tx = tid & 15;
  float acc[4][4] = {};
  for (int k0 = 0; k0 < K; k0 += 16) {
    #pragma unroll
    for (int it = 0; it < 4; ++it) {
      int t = tid + it*256;
      int m = t >> 4, kk = t & 15;
      As[kk][m] = A[(size_t)(m0+m)*K + k0 + kk];
      int o = t >> 4;
      Bs[kk][o] = W[(size_t)(n0+o)*K + k0 + kk];
    }
    __syncthreads();
    #pragma unroll
    for (int kk = 0; kk < 16; ++kk) {
      float4 av = *(const float4*)&As[kk][ty*4];
      float4 bv = *(const float4*)&Bs[kk][tx*4];
      float a[4] = {av.x, av.y, av.z, av.w};
      float bb[4] = {bv.x, bv.y, bv.z, bv.w};
      #pragma unroll
      for (int r = 0; r < 4; ++r)
        #pragma unroll
        for (int c = 0; c < 4; ++c)
          acc[r][c] = fmaf(a[r], bb[c], acc[r][c]);
    }
    __syncthreads();
  }
  #pragma unroll
  for (int r = 0; r < 4; ++r) {
    float4 v; float* vp = (float*)&v;
    #pragma unroll
    for (int c = 0; c < 4; ++c) {
      int o = n0 + tx*4 + c;
      float val = acc[r][c]*g[o] + bias[o];
      vp[c] = do_relu ? fmaxf(val, 0.0f) : val;
    }
    *(float4*)&C[(size_t)(m0 + ty*4 + r)*Nc + n0 + tx*4] = v;
  }
}

// C[m,o] = (sum_k A[m,k]*W[k,o]) * rowscale[m]
__global__ void __launch_bounds__(256) gemm_nn_rowscale(const float* __restrict__ A,
    const float* __restrict__ W, const float* __restrict__ rowscale,
    float* __restrict__ C, int K, int Nc) {
  __shared__ __attribute__((aligned(16))) float As[16][68];
  __shared__ __attribute__((aligned(16))) float Bs[16][68];
  int tid = threadIdx.x;
  int m0 = blockIdx.x * 64, n0 = blockIdx.y * 64;
  int ty = tid >> 4, tx = tid & 15;
  float acc[4][4] = {};
  for (int k0 = 0; k0 < K; k0 += 16) {
    #pragma unroll
    for (int it = 0; it < 4; ++it) {
      int t = tid + it*256;
      int m = t >> 4, kk = t & 15;
      As[kk][m] = A[(size_t)(m0+m)*K + k0 + kk];
      int o2 = t & 63, kk2 = t >> 6;
      Bs[kk2][o2] = W[(size_t)(k0+kk2)*Nc + n0 + o2];
    }
    __syncthreads();
    #pragma unroll
    for (int kk = 0; kk < 16; ++kk) {
      float4 av = *(const float4*)&As[kk][ty*4];
      float4 bv = *(const float4*)&Bs[kk][tx*4];
      float a[4] = {av.x, av.y, av.z, av.w};
      float bb[4] = {bv.x, bv.y, bv.z, bv.w};
      #pragma unroll
      for (int r = 0; r < 4; ++r)
        #pragma unroll
        for (int c = 0; c < 4; ++c)
          acc[r][c] = fmaf(a[r], bb[c], acc[r][c]);
    }
    __syncthreads();
  }
  #pragma unroll
  for (int r = 0; r < 4; ++r) {
    float sc = rowscale[m0 + ty*4 + r];
    float4 v; float* vp = (float*)&v;
    #pragma unroll
    for (int c = 0; c < 4; ++c) vp[c] = acc[r][c]*sc;
    *(float4*)&C[(size_t)(m0 + ty*4 + r)*Nc + n0 + tx*4] = v;
  }
}

// ---------------- GCN aggregate: gather 5 neighbor rows, scale, bias, relu ----------------
__global__ void k_agg(const float* __restrict__ hw, const int* __restrict__ nbr,
                      const float* __restrict__ bias, float* __restrict__ out,
                      int F, int do_relu) {
  int per = F >> 2;
  int gid = blockIdx.x*256 + threadIdx.x;
  int i = gid / per;
  int f = (gid - i*per) * 4;
  const int* nb = nbr + i*KNN;
  float sx=0, sy=0, sz=0, sw=0;
  #pragma unroll
  for (int k = 0; k < KNN; ++k) {
    const float4 v = *(const float4*)&hw[(size_t)nb[k]*F + f];
    sx += v.x; sy += v.y; sz += v.z; sw += v.w;
  }
  const float ninv = 0.44721359549995793f;  // rsqrt(5), deg_in == 5 for every node
  float4 o4;
  o4.x = sx*ninv + bias[f+0];
  o4.y = sy*ninv + bias[f+1];
  o4.z = sz*ninv + bias[f+2];
  o4.w = sw*ninv + bias[f+3];
  if (do_relu) {
    o4.x = fmaxf(o4.x, 0.0f); o4.y = fmaxf(o4.y, 0.0f);
    o4.z = fmaxf(o4.z, 0.0f); o4.w = fmaxf(o4.w, 0.0f);
  }
  *(float4*)&out[(size_t)i*F + f] = o4;
}

// ---------------- global max-pool over 32768 rows of [*,256] ----------------
__global__ void k_maxpool(const float* __restrict__ z, unsigned int* __restrict__ pooled) {
  int o = threadIdx.x;
  int r0 = blockIdx.x * 128;
  float m = 0.0f;  // post-ReLU values are >= 0
  for (int r = 0; r < 128; ++r) m = fmaxf(m, z[(size_t)(r0 + r)*256 + o]);
  atomicMax(&pooled[o], __float_as_uint(m));  // valid: nonneg float bits are order-preserving
}

// ---------------- final 256 -> 128 GEMV ----------------
__global__ void k_fc3(const float* __restrict__ pooled, const float* __restrict__ w,
                      const float* __restrict__ bias, float* __restrict__ out) {
  __shared__ float p[256];
  int tid = threadIdx.x;
  p[tid] = pooled[tid];
  p[tid + 128] = pooled[tid + 128];
  __syncthreads();
  float s = 0.0f;
  for (int i = 0; i < 256; ++i) s = fmaf(w[tid*256 + i], p[i], s);
  out[tid] = s + bias[tid];
}

extern "C" void kernel_launch(void* const* d_in, const int* in_sizes, int n_in,
                              void* d_out, int out_size, void* d_ws, size_t ws_size,
                              hipStream_t stream) {
  const float* pc   = (const float*)d_in[0];
  const float* w1   = (const float*)d_in[1];
  const float* g1   = (const float*)d_in[2];
  const float* b1   = (const float*)d_in[3];
  const float* w2   = (const float*)d_in[4];
  const float* g2   = (const float*)d_in[5];
  const float* b2   = (const float*)d_in[6];
  const float* w3   = (const float*)d_in[7];
  const float* g3   = (const float*)d_in[8];
  const float* b3   = (const float*)d_in[9];
  const float* w4   = (const float*)d_in[10];
  const float* g4   = (const float*)d_in[11];
  const float* b4   = (const float*)d_in[12];
  const float* gc1w = (const float*)d_in[13];
  const float* gc1b = (const float*)d_in[14];
  const float* gc2w = (const float*)d_in[15];
  const float* gc2b = (const float*)d_in[16];
  const float* gc3w = (const float*)d_in[17];
  const float* gc3b = (const float*)d_in[18];
  const float* fc1w = (const float*)d_in[19];
  const float* f1g  = (const float*)d_in[20];
  const float* f1b  = (const float*)d_in[21];
  const float* fc2w = (const float*)d_in[22];
  const float* f2g  = (const float*)d_in[23];
  const float* f2b  = (const float*)d_in[24];
  const float* fc3w = (const float*)d_in[25];
  const float* fc3b = (const float*)d_in[26];
  float* out = (float*)d_out;

  char* wsb = (char*)d_ws;
  size_t off = 0;
  auto alloc = [&](size_t bytes) -> void* {
    void* p = wsb + off;
    off += (bytes + 255) & ~(size_t)255;
    return p;
  };
  int*   ord    = (int*)  alloc((size_t)BN*4);
  int*   deg    = (int*)  alloc((size_t)BN*4);
  int*   nbr    = (int*)  alloc((size_t)BN*KNN*4);
  float* dcent  = (float*)alloc((size_t)BN*4);
  float* normo  = (float*)alloc((size_t)BN*4);
  float* pooled = (float*)alloc(256*4);
  float* bufP   = (float*)alloc((size_t)BN*128*4);  // 16MB
  float* bufQ   = (float*)alloc((size_t)BN*256*4);  // 32MB
  float* bufR   = (float*)alloc((size_t)BN*128*4);  // 16MB
  float* bufS   = (float*)alloc((size_t)BN*256*4);  // 32MB
  float* bufT   = (float*)alloc((size_t)BN*512*4);  // 64MB

  hipMemsetAsync(deg, 0, (size_t)BN*4, stream);
  hipMemsetAsync(pooled, 0, 256*4, stream);

  k_centroid<<<NB, 256, 0, stream>>>(pc, dcent);
  k_rank<<<NB*16, 256, 0, stream>>>(dcent, ord);
  k_knn<<<NB*16, 256, 0, stream>>>(pc, nbr, deg);
  k_norm<<<BN/256, 256, 0, stream>>>(deg, normo);

  // conv stack
  k_conv1<<<BN/4, 256, 0, stream>>>(pc, ord, w1, g1, b1, bufR);                  // h1 [BN,64]
  gemm_nt<<<dim3(BN/64, 1), 256, 0, stream>>>(bufR, w2, g2, b2, bufS, 64, 64, 1);   // h2
  gemm_nt<<<dim3(BN/64, 1), 256, 0, stream>>>(bufS, w3, g3, b3, bufR, 64, 64, 1);   // h3
  gemm_nt<<<dim3(BN/64, 2), 256, 0, stream>>>(bufR, w4, g4, b4, bufP, 64, 128, 1);  // feat [BN,128]

  // GCN 1
  gemm_nn_rowscale<<<dim3(BN/64, 2), 256, 0, stream>>>(bufP, gc1w, normo, bufQ, 128, 128); // hw1
  k_agg<<<(BN*32)/256, 256, 0, stream>>>(bufQ, nbr, gc1b, bufR, 128, 1);                   // g1
  // GCN 2
  gemm_nn_rowscale<<<dim3(BN/64, 2), 256, 0, stream>>>(bufR, gc2w, normo, bufS, 128, 128); // hw2
  k_agg<<<(BN*32)/256, 256, 0, stream>>>(bufS, nbr, gc2b, bufP, 128, 1);                   // g2
  // GCN 3
  gemm_nn_rowscale<<<dim3(BN/64, 4), 256, 0, stream>>>(bufP, gc3w, normo, bufQ, 128, 256); // hw3
  k_agg<<<(BN*64)/256, 256, 0, stream>>>(bufQ, nbr, gc3b, bufS, 256, 0);                   // g3 [BN,256]

  // head
  gemm_nt<<<dim3(BN/64, 8), 256, 0, stream>>>(bufS, fc1w, f1g, f1b, bufT, 256, 512, 1);  // z1 [BN,512]
  gemm_nt<<<dim3(BN/64, 4), 256, 0, stream>>>(bufT, fc2w, f2g, f2b, bufQ, 512, 256, 1);  // z2 [BN,256]
  k_maxpool<<<BN/128, 256, 0, stream>>>(bufQ, (unsigned int*)pooled);
  k_fc3<<<1, 128, 0, stream>>>(pooled, fc3w, fc3b, out);
}

// Round 2
// 672.847 us; speedup vs baseline: 1.5837x; 1.5837x over previous
//
#include <hip/hip_runtime.h>
#include <math.h>
#include <float.h>

#define NB 8
#define NP 4096
#define BN (NB*NP)
#define KNN 5
#define JCH 512
#define NJC (NP/JCH)   // 8 j-chunks

// ---------------- preprocessing ----------------

__global__ void k_centroid(const float* __restrict__ pc, float* __restrict__ dcent) {
  int b = blockIdx.x, tid = threadIdx.x;
  const float* px = pc + (size_t)b*3*NP;
  const float* py = px + NP;
  const float* pz = py + NP;
  double sx=0, sy=0, sz=0;
  for (int n = tid; n < NP; n += 256) { sx += px[n]; sy += py[n]; sz += pz[n]; }
  __shared__ double rx[256], ry[256], rz[256];
  rx[tid]=sx; ry[tid]=sy; rz[tid]=sz;
  __syncthreads();
  for (int s = 128; s > 0; s >>= 1) {
    if (tid < s) { rx[tid]+=rx[tid+s]; ry[tid]+=ry[tid+s]; rz[tid]+=rz[tid+s]; }
    __syncthreads();
  }
  __shared__ float cxs, cys, czs;
  if (tid == 0) {
    cxs = (float)(rx[0]/NP); cys = (float)(ry[0]/NP); czs = (float)(rz[0]/NP);
  }
  __syncthreads();
  float cx = cxs, cy = cys, cz = czs;
  for (int n = tid; n < NP; n += 256) {
    float dx = __fsub_rn(px[n], cx);
    float dy = __fsub_rn(py[n], cy);
    float dz = __fsub_rn(pz[n], cz);
    float d = __fadd_rn(__fadd_rn(__fmul_rn(dx,dx), __fmul_rn(dy,dy)), __fmul_rn(dz,dz));
    dcent[b*NP + n] = d;
  }
}

// ---- chunked stable rank: rank_i = sum_j [(dj<di) || (dj==di && j<i)] ----
__global__ void __launch_bounds__(256) k_rank_part(const float* __restrict__ dcent,
                                                   int* __restrict__ rank) {
  int jc = blockIdx.x, ic = blockIdx.y, b = blockIdx.z;
  __shared__ float d[JCH];
  int j0 = jc*JCH;
  for (int n = threadIdx.x; n < JCH; n += 256) d[n] = dcent[b*NP + j0 + n];
  __syncthreads();
  int i = ic*256 + threadIdx.x;
  float di = dcent[b*NP + i];
  int cnt = 0;
  #pragma unroll 8
  for (int n = 0; n < JCH; ++n) {
    float dj = d[n];
    cnt += (dj < di) || (dj == di && (j0 + n) < i);
  }
  atomicAdd(&rank[b*NP + i], cnt);
}

__global__ void k_scatter(const int* __restrict__ rank, int* __restrict__ ord) {
  int idx = blockIdx.x*256 + threadIdx.x;
  int b = idx >> 12, i = idx & (NP-1);
  ord[b*NP + rank[idx]] = i;   // batch-local source index
}

// ---- chunked KNN: per (i, j-chunk) top-5, then exact merge ----
__global__ void __launch_bounds__(256) k_knn_part(const float* __restrict__ pc,
                                                  float* __restrict__ partd,
                                                  int* __restrict__ parti) {
  int jc = blockIdx.x, ic = blockIdx.y, b = blockIdx.z;
  __shared__ float xs[JCH], ys[JCH], zs[JCH], sq[JCH];
  const float* px = pc + (size_t)b*3*NP;
  int j0 = jc*JCH;
  for (int n = threadIdx.x; n < JCH; n += 256) {
    float x = px[j0+n], y = px[NP+j0+n], z = px[2*NP+j0+n];
    xs[n]=x; ys[n]=y; zs[n]=z;
    sq[n] = __fadd_rn(__fadd_rn(__fmul_rn(x,x), __fmul_rn(y,y)), __fmul_rn(z,z));
  }
  __syncthreads();
  int i = ic*256 + threadIdx.x;
  float xi = px[i], yi = px[NP+i], zi = px[2*NP+i];
  float sqi = __fadd_rn(__fadd_rn(__fmul_rn(xi,xi), __fmul_rn(yi,yi)), __fmul_rn(zi,zi));
  float b0 = FLT_MAX, b1 = FLT_MAX, b2 = FLT_MAX, b3 = FLT_MAX, b4 = FLT_MAX;
  int   i0 = 0, i1 = 0, i2 = 0, i3 = 0, i4 = 0;
  #pragma unroll 4
  for (int n = 0; n < JCH; ++n) {
    float dot = __fadd_rn(__fadd_rn(__fmul_rn(xi,xs[n]), __fmul_rn(yi,ys[n])), __fmul_rn(zi,zs[n]));
    float dist = __fsub_rn(__fadd_rn(sqi, sq[n]), __fmul_rn(2.0f, dot));
    if (dist < b4) {               // strict <: ties keep the earlier (lower) index
      int j = j0 + n;
      if (dist < b3) {
        b4 = b3; i4 = i3;
        if (dist < b2) {
          b3 = b2; i3 = i2;
          if (dist < b1) {
            b2 = b1; i2 = i1;
            if (dist < b0) { b1 = b0; i1 = i0; b0 = dist; i0 = j; }
            else           { b1 = dist; i1 = j; }
          } else { b2 = dist; i2 = j; }
        } else { b3 = dist; i3 = j; }
      } else { b4 = dist; i4 = j; }
    }
  }
  size_t base = ((size_t)(b*NP + i)*NJC + jc)*KNN;
  partd[base+0]=b0; partd[base+1]=b1; partd[base+2]=b2; partd[base+3]=b3; partd[base+4]=b4;
  parti[base+0]=i0; parti[base+1]=i1; parti[base+2]=i2; parti[base+3]=i3; parti[base+4]=i4;
}

__global__ void k_knn_merge(const float* __restrict__ partd, const int* __restrict__ parti,
                            int* __restrict__ nbr, int* __restrict__ deg) {
  int node = blockIdx.x*256 + threadIdx.x;
  float b0 = FLT_MAX, b1 = FLT_MAX, b2 = FLT_MAX, b3 = FLT_MAX, b4 = FLT_MAX;
  int   i0 = 0, i1 = 0, i2 = 0, i3 = 0, i4 = 0;
  size_t base = (size_t)node*NJC*KNN;
  // chunks arrive in increasing-index order; per-chunk lists are (d,idx)-lex
  // sorted; strict-< insertion therefore reproduces global (d,idx)-lex top-5
  #pragma unroll
  for (int c = 0; c < NJC*KNN; ++c) {
    float dist = partd[base + c];
    int   j    = parti[base + c];
    if (dist < b4) {
      if (dist < b3) {
        b4 = b3; i4 = i3;
        if (dist < b2) {
          b3 = b2; i3 = i2;
          if (dist < b1) {
            b2 = b1; i2 = i1;
            if (dist < b0) { b1 = b0; i1 = i0; b0 = dist; i0 = j; }
            else           { b1 = dist; i1 = j; }
          } else { b2 = dist; i2 = j; }
        } else { b3 = dist; i3 = j; }
      } else { b4 = dist; i4 = j; }
    }
  }
  int boff = (node >> 12) * NP;
  int nb = node*KNN;
  nbr[nb+0] = boff + i0;  nbr[nb+1] = boff + i1;  nbr[nb+2] = boff + i2;
  nbr[nb+3] = boff + i3;  nbr[nb+4] = boff + i4;
  atomicAdd(&deg[boff + i0], 1); atomicAdd(&deg[boff + i1], 1);
  atomicAdd(&deg[boff + i2], 1); atomicAdd(&deg[boff + i3], 1);
  atomicAdd(&deg[boff + i4], 1);
}

__global__ void k_norm(const int* __restrict__ deg, float* __restrict__ normo) {
  int i = blockIdx.x*256 + threadIdx.x;
  int d = deg[i]; if (d < 1) d = 1;
  normo[i] = 1.0f / sqrtf((float)d);
}

// ---------------- conv1 (3 -> 64) on sorted points ----------------
__global__ void k_conv1(const float* __restrict__ pc, const int* __restrict__ ord,
                        const float* __restrict__ w, const float* __restrict__ g,
                        const float* __restrict__ bias, float* __restrict__ out) {
  int node = blockIdx.x*4 + (threadIdx.x >> 6);
  int o = threadIdx.x & 63;
  int b = node >> 12;
  int j = ord[node];
  const float* base = pc + (size_t)b*3*NP;
  float x = base[j], y = base[NP + j], z = base[2*NP + j];
  float acc = x*w[o*3+0] + y*w[o*3+1] + z*w[o*3+2];
  float v = acc*g[o] + bias[o];
  out[(size_t)node*64 + o] = fmaxf(v, 0.0f);
}

// ---------------- generic fp32 GEMMs, 64x64 tile, 256 thr, 4x4 micro ----------------
__global__ void __launch_bounds__(256) gemm_nt(const float* __restrict__ A,
    const float* __restrict__ W, const float* __restrict__ g, const float* __restrict__ bias,
    float* __restrict__ C, int K, int Nc, int do_relu) {
  __shared__ __attribute__((aligned(16))) float As[16][68];
  __shared__ __attribute__((aligned(16))) float Bs[16][68];
  int tid = threadIdx.x;
  int m0 = blockIdx.x * 64, n0 = blockIdx.y * 64;
  int ty = tid >> 4, tx = tid & 15;
  float acc[4][4] = {};
  for (int k0 = 0; k0 < K; k0 += 16) {
    #pragma unroll
    for (int it = 0; it < 4; ++it) {
      int t = tid + it*256;
      int m = t >> 4, kk = t & 15;
      As[kk][m] = A[(size_t)(m0+m)*K + k0 + kk];
      int o = t >> 4;
      Bs[kk][o] = W[(size_t)(n0+o)*K + k0 + kk];
    }
    __syncthreads();
    #pragma unroll
    for (int kk = 0; kk < 16; ++kk) {
      float4 av = *(const float4*)&As[kk][ty*4];
      float4 bv = *(const float4*)&Bs[kk][tx*4];
      float a[4] = {av.x, av.y, av.z, av.w};
      float bb[4] = {bv.x, bv.y, bv.z, bv.w};
      #pragma unroll
      for (int r = 0; r < 4; ++r)
        #pragma unroll
        for (int c = 0; c < 4; ++c)
          acc[r][c] = fmaf(a[r], bb[c], acc[r][c]);
    }
    __syncthreads();
  }
  #pragma unroll
  for (int r = 0; r < 4; ++r) {
    float4 v; float* vp = (float*)&v;
    #pragma unroll
    for (int c = 0; c < 4; ++c) {
      int o = n0 + tx*4 + c;
      float val = acc[r][c]*g[o] + bias[o];
      vp[c] = do_relu ? fmaxf(val, 0.0f) : val;
    }
    *(float4*)&C[(size_t)(m0 + ty*4 + r)*Nc + n0 + tx*4] = v;
  }
}

__global__ void __launch_bounds__(256) gemm_nn_rowscale(const float* __restrict__ A,
    const float* __restrict__ W, const float* __restrict__ rowscale,
    float* __restrict__ C, int K, int Nc) {
  __shared__ __attribute__((aligned(16))) float As[16][68];
  __shared__ __attribute__((aligned(16))) float Bs[16][68];
  int tid = threadIdx.x;
  int m0 = blockIdx.x * 64, n0 = blockIdx.y * 64;
  int ty = tid >> 4, tx = tid & 15;
  float acc[4][4] = {};
  for (int k0 = 0; k0 < K; k0 += 16) {
    #pragma unroll
    for (int it = 0; it < 4; ++it) {
      int t = tid + it*256;
      int m = t >> 4, kk = t & 15;
      As[kk][m] = A[(size_t)(m0+m)*K + k0 + kk];
      int o2 = t & 63, kk2 = t >> 6;
      Bs[kk2][o2] = W[(size_t)(k0+kk2)*Nc + n0 + o2];
    }
    __syncthreads();
    #pragma unroll
    for (int kk = 0; kk < 16; ++kk) {
      float4 av = *(const float4*)&As[kk][ty*4];
      float4 bv = *(const float4*)&Bs[kk][tx*4];
      float a[4] = {av.x, av.y, av.z, av.w};
      float bb[4] = {bv.x, bv.y, bv.z, bv.w};
      #pragma unroll
      for (int r = 0; r < 4; ++r)
        #pragma unroll
        for (int c = 0; c < 4; ++c)
          acc[r][c] = fmaf(a[r], bb[c], acc[r][c]);
    }
    __syncthreads();
  }
  #pragma unroll
  for (int r = 0; r < 4; ++r) {
    float sc = rowscale[m0 + ty*4 + r];
    float4 v; float* vp = (float*)&v;
    #pragma unroll
    for (int c = 0; c < 4; ++c) vp[c] = acc[r][c]*sc;
    *(float4*)&C[(size_t)(m0 + ty*4 + r)*Nc + n0 + tx*4] = v;
  }
}

// ---------------- GCN aggregate ----------------
__global__ void k_agg(const float* __restrict__ hw, const int* __restrict__ nbr,
                      const float* __restrict__ bias, float* __restrict__ out,
                      int F, int do_relu) {
  int per = F >> 2;
  int gid = blockIdx.x*256 + threadIdx.x;
  int i = gid / per;
  int f = (gid - i*per) * 4;
  const int* nb = nbr + i*KNN;
  float sx=0, sy=0, sz=0, sw=0;
  #pragma unroll
  for (int k = 0; k < KNN; ++k) {
    const float4 v = *(const float4*)&hw[(size_t)nb[k]*F + f];
    sx += v.x; sy += v.y; sz += v.z; sw += v.w;
  }
  const float ninv = 0.44721359549995793f;  // rsqrt(5): deg_in == 5 always
  float4 o4;
  o4.x = sx*ninv + bias[f+0];
  o4.y = sy*ninv + bias[f+1];
  o4.z = sz*ninv + bias[f+2];
  o4.w = sw*ninv + bias[f+3];
  if (do_relu) {
    o4.x = fmaxf(o4.x, 0.0f); o4.y = fmaxf(o4.y, 0.0f);
    o4.z = fmaxf(o4.z, 0.0f); o4.w = fmaxf(o4.w, 0.0f);
  }
  *(float4*)&out[(size_t)i*F + f] = o4;
}

// ---------------- global max-pool ----------------
__global__ void k_maxpool(const float* __restrict__ z, unsigned int* __restrict__ pooled) {
  int o = threadIdx.x;
  int r0 = blockIdx.x * 128;
  float m = 0.0f;  // post-ReLU values are >= 0
  for (int r = 0; r < 128; ++r) m = fmaxf(m, z[(size_t)(r0 + r)*256 + o]);
  atomicMax(&pooled[o], __float_as_uint(m));
}

// ---------------- final 256 -> 128 GEMV ----------------
__global__ void k_fc3(const float* __restrict__ pooled, const float* __restrict__ w,
                      const float* __restrict__ bias, float* __restrict__ out) {
  __shared__ float p[256];
  int tid = threadIdx.x;
  p[tid] = pooled[tid];
  p[tid + 128] = pooled[tid + 128];
  __syncthreads();
  float s = 0.0f;
  for (int i = 0; i < 256; ++i) s = fmaf(w[tid*256 + i], p[i], s);
  out[tid] = s + bias[tid];
}

extern "C" void kernel_launch(void* const* d_in, const int* in_sizes, int n_in,
                              void* d_out, int out_size, void* d_ws, size_t ws_size,
                              hipStream_t stream) {
  const float* pc   = (const float*)d_in[0];
  const float* w1   = (const float*)d_in[1];
  const float* g1   = (const float*)d_in[2];
  const float* b1   = (const float*)d_in[3];
  const float* w2   = (const float*)d_in[4];
  const float* g2   = (const float*)d_in[5];
  const float* b2   = (const float*)d_in[6];
  const float* w3   = (const float*)d_in[7];
  const float* g3   = (const float*)d_in[8];
  const float* b3   = (const float*)d_in[9];
  const float* w4   = (const float*)d_in[10];
  const float* g4   = (const float*)d_in[11];
  const float* b4   = (const float*)d_in[12];
  const float* gc1w = (const float*)d_in[13];
  const float* gc1b = (const float*)d_in[14];
  const float* gc2w = (const float*)d_in[15];
  const float* gc2b = (const float*)d_in[16];
  const float* gc3w = (const float*)d_in[17];
  const float* gc3b = (const float*)d_in[18];
  const float* fc1w = (const float*)d_in[19];
  const float* f1g  = (const float*)d_in[20];
  const float* f1b  = (const float*)d_in[21];
  const float* fc2w = (const float*)d_in[22];
  const float* f2g  = (const float*)d_in[23];
  const float* f2b  = (const float*)d_in[24];
  const float* fc3w = (const float*)d_in[25];
  const float* fc3b = (const float*)d_in[26];
  float* out = (float*)d_out;

  char* wsb = (char*)d_ws;
  size_t off = 0;
  auto alloc = [&](size_t bytes) -> void* {
    void* p = wsb + off;
    off += (bytes + 255) & ~(size_t)255;
    return p;
  };
  int*   ord    = (int*)  alloc((size_t)BN*4);
  int*   deg    = (int*)  alloc((size_t)BN*4);
  int*   rankb  = (int*)  alloc((size_t)BN*4);
  int*   nbr    = (int*)  alloc((size_t)BN*KNN*4);
  float* dcent  = (float*)alloc((size_t)BN*4);
  float* normo  = (float*)alloc((size_t)BN*4);
  float* pooled = (float*)alloc(256*4);
  float* bufP   = (float*)alloc((size_t)BN*128*4);  // 16MB
  float* bufQ   = (float*)alloc((size_t)BN*256*4);  // 32MB
  float* bufR   = (float*)alloc((size_t)BN*128*4);  // 16MB
  float* bufS   = (float*)alloc((size_t)BN*256*4);  // 32MB
  float* bufT   = (float*)alloc((size_t)BN*512*4);  // 64MB
  // KNN partial scratch aliased into bufT (bufT first written much later, at fc1)
  float* partd = bufT;
  int*   parti = (int*)(bufT + (size_t)BN*NJC*KNN);

  hipMemsetAsync(deg, 0, (size_t)BN*4, stream);
  hipMemsetAsync(rankb, 0, (size_t)BN*4, stream);
  hipMemsetAsync(pooled, 0, 256*4, stream);

  k_centroid<<<NB, 256, 0, stream>>>(pc, dcent);
  k_rank_part<<<dim3(NJC, NP/256, NB), 256, 0, stream>>>(dcent, rankb);
  k_scatter<<<BN/256, 256, 0, stream>>>(rankb, ord);
  k_knn_part<<<dim3(NJC, NP/256, NB), 256, 0, stream>>>(pc, partd, parti);
  k_knn_merge<<<BN/256, 256, 0, stream>>>(partd, parti, nbr, deg);
  k_norm<<<BN/256, 256, 0, stream>>>(deg, normo);

  // conv stack
  k_conv1<<<BN/4, 256, 0, stream>>>(pc, ord, w1, g1, b1, bufR);                     // h1 [BN,64]
  gemm_nt<<<dim3(BN/64, 1), 256, 0, stream>>>(bufR, w2, g2, b2, bufS, 64, 64, 1);   // h2
  gemm_nt<<<dim3(BN/64, 1), 256, 0, stream>>>(bufS, w3, g3, b3, bufR, 64, 64, 1);   // h3
  gemm_nt<<<dim3(BN/64, 2), 256, 0, stream>>>(bufR, w4, g4, b4, bufP, 64, 128, 1);  // feat [BN,128]

  // GCN 1
  gemm_nn_rowscale<<<dim3(BN/64, 2), 256, 0, stream>>>(bufP, gc1w, normo, bufQ, 128, 128);
  k_agg<<<(BN*32)/256, 256, 0, stream>>>(bufQ, nbr, gc1b, bufR, 128, 1);
  // GCN 2
  gemm_nn_rowscale<<<dim3(BN/64, 2), 256, 0, stream>>>(bufR, gc2w, normo, bufS, 128, 128);
  k_agg<<<(BN*32)/256, 256, 0, stream>>>(bufS, nbr, gc2b, bufP, 128, 1);
  // GCN 3
  gemm_nn_rowscale<<<dim3(BN/64, 4), 256, 0, stream>>>(bufP, gc3w, normo, bufQ, 128, 256);
  k_agg<<<(BN*64)/256, 256, 0, stream>>>(bufQ, nbr, gc3b, bufS, 256, 0);            // g3 [BN,256]

  // head
  gemm_nt<<<dim3(BN/64, 8), 256, 0, stream>>>(bufS, fc1w, f1g, f1b, bufT, 256, 512, 1);  // z1 [BN,512]
  gemm_nt<<<dim3(BN/64, 4), 256, 0, stream>>>(bufT, fc2w, f2g, f2b, bufQ, 512, 256, 1);  // z2 [BN,256]
  k_maxpool<<<BN/128, 256, 0, stream>>>(bufQ, (unsigned int*)pooled);
  k_fc3<<<1, 128, 0, stream>>>(pooled, fc3w, fc3b, out);
}

// Round 3
// 440.492 us; speedup vs baseline: 2.4191x; 1.5275x over previous
//
#include <hip/hip_runtime.h>
#include <math.h>
#include <float.h>

#define NB 8
#define NP 4096
#define BN_ (NB*NP)
#define KNN 5
#define JCH 512
#define NJC (NP/JCH)   // 8 j-chunks

typedef unsigned short u16;
typedef __attribute__((ext_vector_type(8))) __bf16 bf16x8;
typedef __attribute__((ext_vector_type(4))) float f32x4;

__device__ __forceinline__ u16 f2bf(float x){
  unsigned u = __float_as_uint(x);
  u += 0x7fff + ((u>>16)&1);          // RNE
  return (u16)(u>>16);
}
__device__ __forceinline__ float bf2f(u16 h){ return __uint_as_float(((unsigned)h)<<16); }

// ---------------- preprocessing (exact fp32, unchanged) ----------------

__global__ void k_centroid(const float* __restrict__ pc, float* __restrict__ dcent) {
  int b = blockIdx.x, tid = threadIdx.x;
  const float* px = pc + (size_t)b*3*NP;
  const float* py = px + NP;
  const float* pz = py + NP;
  double sx=0, sy=0, sz=0;
  for (int n = tid; n < NP; n += 256) { sx += px[n]; sy += py[n]; sz += pz[n]; }
  __shared__ double rx[256], ry[256], rz[256];
  rx[tid]=sx; ry[tid]=sy; rz[tid]=sz;
  __syncthreads();
  for (int s = 128; s > 0; s >>= 1) {
    if (tid < s) { rx[tid]+=rx[tid+s]; ry[tid]+=ry[tid+s]; rz[tid]+=rz[tid+s]; }
    __syncthreads();
  }
  __shared__ float cxs, cys, czs;
  if (tid == 0) {
    cxs = (float)(rx[0]/NP); cys = (float)(ry[0]/NP); czs = (float)(rz[0]/NP);
  }
  __syncthreads();
  float cx = cxs, cy = cys, cz = czs;
  for (int n = tid; n < NP; n += 256) {
    float dx = __fsub_rn(px[n], cx);
    float dy = __fsub_rn(py[n], cy);
    float dz = __fsub_rn(pz[n], cz);
    float d = __fadd_rn(__fadd_rn(__fmul_rn(dx,dx), __fmul_rn(dy,dy)), __fmul_rn(dz,dz));
    dcent[b*NP + n] = d;
  }
}

__global__ void __launch_bounds__(256) k_rank_part(const float* __restrict__ dcent,
                                                   int* __restrict__ rank) {
  int jc = blockIdx.x, ic = blockIdx.y, b = blockIdx.z;
  __shared__ float d[JCH];
  int j0 = jc*JCH;
  for (int n = threadIdx.x; n < JCH; n += 256) d[n] = dcent[b*NP + j0 + n];
  __syncthreads();
  int i = ic*256 + threadIdx.x;
  float di = dcent[b*NP + i];
  int cnt = 0;
  #pragma unroll 8
  for (int n = 0; n < JCH; ++n) {
    float dj = d[n];
    cnt += (dj < di) || (dj == di && (j0 + n) < i);
  }
  atomicAdd(&rank[b*NP + i], cnt);
}

__global__ void k_scatter(const int* __restrict__ rank, int* __restrict__ ord) {
  int idx = blockIdx.x*256 + threadIdx.x;
  int b = idx >> 12, i = idx & (NP-1);
  ord[b*NP + rank[idx]] = i;
}

__global__ void __launch_bounds__(256) k_knn_part(const float* __restrict__ pc,
                                                  float* __restrict__ partd,
                                                  int* __restrict__ parti) {
  int jc = blockIdx.x, ic = blockIdx.y, b = blockIdx.z;
  __shared__ float xs[JCH], ys[JCH], zs[JCH], sq[JCH];
  const float* px = pc + (size_t)b*3*NP;
  int j0 = jc*JCH;
  for (int n = threadIdx.x; n < JCH; n += 256) {
    float x = px[j0+n], y = px[NP+j0+n], z = px[2*NP+j0+n];
    xs[n]=x; ys[n]=y; zs[n]=z;
    sq[n] = __fadd_rn(__fadd_rn(__fmul_rn(x,x), __fmul_rn(y,y)), __fmul_rn(z,z));
  }
  __syncthreads();
  int i = ic*256 + threadIdx.x;
  float xi = px[i], yi = px[NP+i], zi = px[2*NP+i];
  float sqi = __fadd_rn(__fadd_rn(__fmul_rn(xi,xi), __fmul_rn(yi,yi)), __fmul_rn(zi,zi));
  float b0 = FLT_MAX, b1 = FLT_MAX, b2 = FLT_MAX, b3 = FLT_MAX, b4 = FLT_MAX;
  int   i0 = 0, i1 = 0, i2 = 0, i3 = 0, i4 = 0;
  #pragma unroll 4
  for (int n = 0; n < JCH; ++n) {
    float dot = __fadd_rn(__fadd_rn(__fmul_rn(xi,xs[n]), __fmul_rn(yi,ys[n])), __fmul_rn(zi,zs[n]));
    float dist = __fsub_rn(__fadd_rn(sqi, sq[n]), __fmul_rn(2.0f, dot));
    if (dist < b4) {
      int j = j0 + n;
      if (dist < b3) {
        b4 = b3; i4 = i3;
        if (dist < b2) {
          b3 = b2; i3 = i2;
          if (dist < b1) {
            b2 = b1; i2 = i1;
            if (dist < b0) { b1 = b0; i1 = i0; b0 = dist; i0 = j; }
            else           { b1 = dist; i1 = j; }
          } else { b2 = dist; i2 = j; }
        } else { b3 = dist; i3 = j; }
      } else { b4 = dist; i4 = j; }
    }
  }
  size_t base = ((size_t)(b*NP + i)*NJC + jc)*KNN;
  partd[base+0]=b0; partd[base+1]=b1; partd[base+2]=b2; partd[base+3]=b3; partd[base+4]=b4;
  parti[base+0]=i0; parti[base+1]=i1; parti[base+2]=i2; parti[base+3]=i3; parti[base+4]=i4;
}

__global__ void k_knn_merge(const float* __restrict__ partd, const int* __restrict__ parti,
                            int* __restrict__ nbr, int* __restrict__ deg) {
  int node = blockIdx.x*256 + threadIdx.x;
  float b0 = FLT_MAX, b1 = FLT_MAX, b2 = FLT_MAX, b3 = FLT_MAX, b4 = FLT_MAX;
  int   i0 = 0, i1 = 0, i2 = 0, i3 = 0, i4 = 0;
  size_t base = (size_t)node*NJC*KNN;
  #pragma unroll
  for (int c = 0; c < NJC*KNN; ++c) {
    float dist = partd[base + c];
    int   j    = parti[base + c];
    if (dist < b4) {
      if (dist < b3) {
        b4 = b3; i4 = i3;
        if (dist < b2) {
          b3 = b2; i3 = i2;
          if (dist < b1) {
            b2 = b1; i2 = i1;
            if (dist < b0) { b1 = b0; i1 = i0; b0 = dist; i0 = j; }
            else           { b1 = dist; i1 = j; }
          } else { b2 = dist; i2 = j; }
        } else { b3 = dist; i3 = j; }
      } else { b4 = dist; i4 = j; }
    }
  }
  int boff = (node >> 12) * NP;
  int nb = node*KNN;
  nbr[nb+0] = boff + i0;  nbr[nb+1] = boff + i1;  nbr[nb+2] = boff + i2;
  nbr[nb+3] = boff + i3;  nbr[nb+4] = boff + i4;
  atomicAdd(&deg[boff + i0], 1); atomicAdd(&deg[boff + i1], 1);
  atomicAdd(&deg[boff + i2], 1); atomicAdd(&deg[boff + i3], 1);
  atomicAdd(&deg[boff + i4], 1);
}

__global__ void k_norm(const int* __restrict__ deg, float* __restrict__ normo) {
  int i = blockIdx.x*256 + threadIdx.x;
  int d = deg[i]; if (d < 1) d = 1;
  normo[i] = 1.0f / sqrtf((float)d);
}

// ---------------- weight prep: fp32 -> bf16 (optionally transposed) ----------------
__global__ void k_cvt(const float* __restrict__ in, u16* __restrict__ outp, int n) {
  int i = blockIdx.x*256 + threadIdx.x;
  if (i < n) outp[i] = f2bf(in[i]);
}
// in [K,N] -> out [N,K]
__global__ void k_cvt_t(const float* __restrict__ in, u16* __restrict__ outp, int K, int N) {
  int idx = blockIdx.x*256 + threadIdx.x;
  if (idx < K*N) {
    int n = idx / K, k = idx - n*K;
    outp[idx] = f2bf(in[k*N + n]);
  }
}

// ---------------- conv1 (3 -> 64), bf16 out ----------------
__global__ void k_conv1(const float* __restrict__ pc, const int* __restrict__ ord,
                        const float* __restrict__ w, const float* __restrict__ g,
                        const float* __restrict__ bias, u16* __restrict__ outp) {
  int node = blockIdx.x*4 + (threadIdx.x >> 6);
  int o = threadIdx.x & 63;
  int b = node >> 12;
  int j = ord[node];
  const float* base = pc + (size_t)b*3*NP;
  float x = base[j], y = base[NP + j], z = base[2*NP + j];
  float acc = x*w[o*3+0] + y*w[o*3+1] + z*w[o*3+2];
  float v = fmaxf(acc*g[o] + bias[o], 0.0f);
  outp[(size_t)node*64 + o] = f2bf(v);
}

// ---------------- bf16 MFMA GEMM: C = act(A[M,K] * W[N,K]^T) ----------------
// BM=128, BN in {64,128}, BK=64. 4 waves, each computing 64 x (BN/2).
// mode 0: bf16 out = relu(acc*gamma[col]+beta[col])
// mode 1: bf16 out = acc*rowscale[row]
// mode 2: fp32 out = relu(acc*gamma[col]+beta[col])
template<int BNT>
__global__ __launch_bounds__(256) void gemm_bf16(
    const u16* __restrict__ A, const u16* __restrict__ W,
    const float* __restrict__ gamma, const float* __restrict__ beta,
    const float* __restrict__ rowscale, void* __restrict__ Cout,
    int K, int Nc, int mode) {
  constexpr int NF = BNT/32;          // n-fragments per wave
  __shared__ u16 As[128*64];
  __shared__ u16 Bs[BNT*64];
  const int tid = threadIdx.x;
  const int w = tid >> 6, l = tid & 63;
  const int m0 = blockIdx.x*128, n0 = blockIdx.y*BNT;
  const int wm = w & 1, wn = w >> 1;
  const int lr = l >> 3;              // row within 8-row group
  const int lc = l & 7;               // k-chunk (8 bf16 = 16B)
  const int fm = l & 15, fk = l >> 4; // MFMA fragment lane decomposition

  f32x4 acc[4][NF];
  #pragma unroll
  for (int i=0;i<4;++i)
    #pragma unroll
    for (int j=0;j<NF;++j) acc[i][j] = (f32x4){0.f,0.f,0.f,0.f};

  for (int k0 = 0; k0 < K; k0 += 64) {
    // stage A tile 128x64 (xor-swizzled: slot = chunk ^ (row&7))
    #pragma unroll
    for (int t=0;t<4;++t){
      int row = (w*4 + t)*8 + lr;
      uint4 v = *(const uint4*)(A + ((size_t)(m0+row)*K + k0 + lc*8));
      *(uint4*)&As[row*64 + ((lc ^ (row&7))*8)] = v;
    }
    // stage B tile BNTx64
    #pragma unroll
    for (int t=0;t<NF;++t){
      int row = (w*NF + t)*8 + lr;
      uint4 v = *(const uint4*)(W + ((size_t)(n0+row)*K + k0 + lc*8));
      *(uint4*)&Bs[row*64 + ((lc ^ (row&7))*8)] = v;
    }
    __syncthreads();
    #pragma unroll
    for (int ks=0; ks<2; ++ks){
      bf16x8 af[4], bfr[NF];
      #pragma unroll
      for (int mf=0; mf<4; ++mf){
        int row = wm*64 + mf*16 + fm;
        int ck = ks*4 + fk;
        af[mf] = *(const bf16x8*)&As[row*64 + ((ck ^ (row&7))*8)];
      }
      #pragma unroll
      for (int nf=0; nf<NF; ++nf){
        int row = wn*(BNT/2) + nf*16 + fm;
        int ck = ks*4 + fk;
        bfr[nf] = *(const bf16x8*)&Bs[row*64 + ((ck ^ (row&7))*8)];
      }
      #pragma unroll
      for (int mf=0; mf<4; ++mf)
        #pragma unroll
        for (int nf=0; nf<NF; ++nf)
          acc[mf][nf] = __builtin_amdgcn_mfma_f32_16x16x32_bf16(af[mf], bfr[nf], acc[mf][nf], 0, 0, 0);
    }
    __syncthreads();
  }

  const int col_base = n0 + wn*(BNT/2);
  if (mode == 1) {
    u16* C = (u16*)Cout;
    #pragma unroll
    for (int mf=0; mf<4; ++mf){
      #pragma unroll
      for (int r=0;r<4;++r){
        int row = m0 + wm*64 + mf*16 + fk*4 + r;
        float rs = rowscale[row];
        #pragma unroll
        for (int nf=0;nf<NF;++nf){
          int col = col_base + nf*16 + fm;
          C[(size_t)row*Nc + col] = f2bf(acc[mf][nf][r]*rs);
        }
      }
    }
  } else {
    float gv[NF], bv[NF];
    #pragma unroll
    for (int nf=0;nf<NF;++nf){
      int col = col_base + nf*16 + fm;
      gv[nf] = gamma[col]; bv[nf] = beta[col];
    }
    #pragma unroll
    for (int mf=0; mf<4; ++mf){
      #pragma unroll
      for (int r=0;r<4;++r){
        int row = m0 + wm*64 + mf*16 + fk*4 + r;
        #pragma unroll
        for (int nf=0;nf<NF;++nf){
          int col = col_base + nf*16 + fm;
          float v = fmaxf(acc[mf][nf][r]*gv[nf] + bv[nf], 0.f);
          if (mode == 0) ((u16*)Cout)[(size_t)row*Nc + col] = f2bf(v);
          else           ((float*)Cout)[(size_t)row*Nc + col] = v;
        }
      }
    }
  }
}

// ---------------- GCN aggregate (bf16 in/out, fp32 math) ----------------
__global__ void k_agg_bf(const u16* __restrict__ hw, const int* __restrict__ nbr,
                         const float* __restrict__ bias, u16* __restrict__ outp,
                         int F, int do_relu) {
  int per = F >> 3;
  int gid = blockIdx.x*256 + threadIdx.x;
  int i = gid / per;
  int f = (gid - i*per) * 8;
  const int* nb = nbr + i*KNN;
  float s[8] = {0,0,0,0,0,0,0,0};
  #pragma unroll
  for (int k = 0; k < KNN; ++k) {
    uint4 v = *(const uint4*)(hw + (size_t)nb[k]*F + f);
    const u16* h = (const u16*)&v;
    #pragma unroll
    for (int j=0;j<8;++j) s[j] += bf2f(h[j]);
  }
  const float ninv = 0.44721359549995793f;  // rsqrt(5): deg_in == 5 always
  u16 o[8];
  #pragma unroll
  for (int j=0;j<8;++j){
    float v = s[j]*ninv + bias[f+j];
    if (do_relu) v = fmaxf(v, 0.f);
    o[j] = f2bf(v);
  }
  *(uint4*)&outp[(size_t)i*F + f] = *(const uint4*)o;
}

// ---------------- global max-pool (fp32 z2) ----------------
__global__ void k_maxpool(const float* __restrict__ z, unsigned int* __restrict__ pooled) {
  int o = threadIdx.x;
  int r0 = blockIdx.x * 128;
  float m = 0.0f;  // post-ReLU values are >= 0
  for (int r = 0; r < 128; ++r) m = fmaxf(m, z[(size_t)(r0 + r)*256 + o]);
  atomicMax(&pooled[o], __float_as_uint(m));
}

// ---------------- final 256 -> 128 GEMV (fp32) ----------------
__global__ void k_fc3(const float* __restrict__ pooled, const float* __restrict__ w,
                      const float* __restrict__ bias, float* __restrict__ outp) {
  __shared__ float p[256];
  int tid = threadIdx.x;
  p[tid] = pooled[tid];
  p[tid + 128] = pooled[tid + 128];
  __syncthreads();
  float s = 0.0f;
  for (int i = 0; i < 256; ++i) s = fmaf(w[tid*256 + i], p[i], s);
  outp[tid] = s + bias[tid];
}

extern "C" void kernel_launch(void* const* d_in, const int* in_sizes, int n_in,
                              void* d_out, int out_size, void* d_ws, size_t ws_size,
                              hipStream_t stream) {
  const float* pc   = (const float*)d_in[0];
  const float* w1   = (const float*)d_in[1];
  const float* g1   = (const float*)d_in[2];
  const float* b1   = (const float*)d_in[3];
  const float* w2   = (const float*)d_in[4];
  const float* g2   = (const float*)d_in[5];
  const float* b2   = (const float*)d_in[6];
  const float* w3   = (const float*)d_in[7];
  const float* g3   = (const float*)d_in[8];
  const float* b3   = (const float*)d_in[9];
  const float* w4   = (const float*)d_in[10];
  const float* g4   = (const float*)d_in[11];
  const float* b4   = (const float*)d_in[12];
  const float* gc1w = (const float*)d_in[13];
  const float* gc1b = (const float*)d_in[14];
  const float* gc2w = (const float*)d_in[15];
  const float* gc2b = (const float*)d_in[16];
  const float* gc3w = (const float*)d_in[17];
  const float* gc3b = (const float*)d_in[18];
  const float* fc1w = (const float*)d_in[19];
  const float* f1g  = (const float*)d_in[20];
  const float* f1b  = (const float*)d_in[21];
  const float* fc2w = (const float*)d_in[22];
  const float* f2g  = (const float*)d_in[23];
  const float* f2b  = (const float*)d_in[24];
  const float* fc3w = (const float*)d_in[25];
  const float* fc3b = (const float*)d_in[26];
  float* outp = (float*)d_out;

  char* wsb = (char*)d_ws;
  size_t off = 0;
  auto alloc = [&](size_t bytes) -> void* {
    void* p = wsb + off;
    off += (bytes + 255) & ~(size_t)255;
    return p;
  };
  int*   ord    = (int*)  alloc((size_t)BN_*4);
  int*   deg    = (int*)  alloc((size_t)BN_*4);
  int*   rankb  = (int*)  alloc((size_t)BN_*4);
  int*   nbr    = (int*)  alloc((size_t)BN_*KNN*4);
  float* dcent  = (float*)alloc((size_t)BN_*4);
  float* normo  = (float*)alloc((size_t)BN_*4);
  float* pooled = (float*)alloc(256*4);
  float* partd  = (float*)alloc((size_t)BN_*NJC*KNN*4);
  int*   parti  = (int*)  alloc((size_t)BN_*NJC*KNN*4);
  // bf16 weights
  u16* wb2   = (u16*)alloc(64*64*2);
  u16* wb3   = (u16*)alloc(64*64*2);
  u16* wb4   = (u16*)alloc(128*64*2);
  u16* wgc1  = (u16*)alloc(128*128*2);
  u16* wgc2  = (u16*)alloc(128*128*2);
  u16* wgc3  = (u16*)alloc(256*128*2);
  u16* wfc1  = (u16*)alloc(512*256*2);
  u16* wfc2  = (u16*)alloc(256*512*2);
  // bf16 activations
  u16* h1   = (u16*)alloc((size_t)BN_*64*2);    // 4MB
  u16* h2   = (u16*)alloc((size_t)BN_*64*2);    // 4MB
  u16* feat = (u16*)alloc((size_t)BN_*128*2);   // 8MB
  u16* hw   = (u16*)alloc((size_t)BN_*256*2);   // 16MB (gc pre-agg, max width 256)
  u16* gb1  = (u16*)alloc((size_t)BN_*128*2);   // 8MB
  u16* g3b  = (u16*)alloc((size_t)BN_*256*2);   // 16MB
  u16* z1   = (u16*)alloc((size_t)BN_*512*2);   // 32MB
  float* z2 = (float*)alloc((size_t)BN_*256*4); // 32MB

  hipMemsetAsync(deg, 0, (size_t)BN_*4, stream);
  hipMemsetAsync(rankb, 0, (size_t)BN_*4, stream);
  hipMemsetAsync(pooled, 0, 256*4, stream);

  // weight conversion (tiny)
  k_cvt<<<16, 256, 0, stream>>>(w2, wb2, 64*64);
  k_cvt<<<16, 256, 0, stream>>>(w3, wb3, 64*64);
  k_cvt<<<32, 256, 0, stream>>>(w4, wb4, 128*64);
  k_cvt_t<<<64, 256, 0, stream>>>(gc1w, wgc1, 128, 128);
  k_cvt_t<<<64, 256, 0, stream>>>(gc2w, wgc2, 128, 128);
  k_cvt_t<<<128, 256, 0, stream>>>(gc3w, wgc3, 128, 256);
  k_cvt<<<512, 256, 0, stream>>>(fc1w, wfc1, 512*256);
  k_cvt<<<512, 256, 0, stream>>>(fc2w, wfc2, 256*512);

  // preprocessing (exact fp32)
  k_centroid<<<NB, 256, 0, stream>>>(pc, dcent);
  k_rank_part<<<dim3(NJC, NP/256, NB), 256, 0, stream>>>(dcent, rankb);
  k_scatter<<<BN_/256, 256, 0, stream>>>(rankb, ord);
  k_knn_part<<<dim3(NJC, NP/256, NB), 256, 0, stream>>>(pc, partd, parti);
  k_knn_merge<<<BN_/256, 256, 0, stream>>>(partd, parti, nbr, deg);
  k_norm<<<BN_/256, 256, 0, stream>>>(deg, normo);

  // conv stack (bf16 MFMA)
  k_conv1<<<BN_/4, 256, 0, stream>>>(pc, ord, w1, g1, b1, h1);
  gemm_bf16<64><<<dim3(BN_/128, 1), 256, 0, stream>>>(h1, wb2, g2, b2, nullptr, h2, 64, 64, 0);
  gemm_bf16<64><<<dim3(BN_/128, 1), 256, 0, stream>>>(h2, wb3, g3, b3, nullptr, h1, 64, 64, 0);
  gemm_bf16<128><<<dim3(BN_/128, 1), 256, 0, stream>>>(h1, wb4, g4, b4, nullptr, feat, 64, 128, 0);

  // GCN 1
  gemm_bf16<128><<<dim3(BN_/128, 1), 256, 0, stream>>>(feat, wgc1, nullptr, nullptr, normo, hw, 128, 128, 1);
  k_agg_bf<<<(BN_*16)/256, 256, 0, stream>>>(hw, nbr, gc1b, gb1, 128, 1);
  // GCN 2
  gemm_bf16<128><<<dim3(BN_/128, 1), 256, 0, stream>>>(gb1, wgc2, nullptr, nullptr, normo, hw, 128, 128, 1);
  k_agg_bf<<<(BN_*16)/256, 256, 0, stream>>>(hw, nbr, gc2b, feat, 128, 1);
  // GCN 3
  gemm_bf16<128><<<dim3(BN_/128, 2), 256, 0, stream>>>(feat, wgc3, nullptr, nullptr, normo, hw, 128, 256, 1);
  k_agg_bf<<<(BN_*32)/256, 256, 0, stream>>>(hw, nbr, gc3b, g3b, 256, 0);

  // head
  gemm_bf16<128><<<dim3(BN_/128, 4), 256, 0, stream>>>(g3b, wfc1, f1g, f1b, nullptr, z1, 256, 512, 0);
  gemm_bf16<128><<<dim3(BN_/128, 2), 256, 0, stream>>>(z1, wfc2, f2g, f2b, nullptr, z2, 512, 256, 2);
  k_maxpool<<<BN_/128, 256, 0, stream>>>(z2, (unsigned int*)pooled);
  k_fc3<<<1, 128, 0, stream>>>(pooled, fc3w, fc3b, outp);
}